// Round 1
// baseline (508.865 us; speedup 1.0000x reference)
//
#include <hip/hip_runtime.h>
#include <hip/hip_bf16.h>

// CausalSelfAttention: B=4 T=2048 C=1024 H=16 D=64
// ws layout (bytes):
//   xb   @ 0         : x as bf16           [8192][1024]   16 MB
//   wat  @ 16777216  : w_attn^T bf16       [3072][1024]    6 MB
//   wpt  @ 23068672  : w_proj^T bf16       [1024][1024]    2 MB
//   Qb   @ 25165824  : Q bf16  [B,H,T,D]                  16 MB
//   Kb   @ 41943040  : K bf16  [B,H,T,D]                  16 MB
//   Vtb  @ 58720256  : V^T bf16 [B,H,D,T]                 16 MB
//   Ob   @ 75497472  : attn out bf16 [8192][1024]         16 MB
// total 92274688 B

typedef float f32x4 __attribute__((ext_vector_type(4)));
typedef short short8 __attribute__((ext_vector_type(8)));
typedef short short4v __attribute__((ext_vector_type(4)));

__device__ __forceinline__ short f2bf(float f) {
  union { __hip_bfloat16 h; short s; } u;
  u.h = __float2bfloat16(f);
  return u.s;
}

__device__ __forceinline__ void gl_lds16(const void* g, void* l) {
  __builtin_amdgcn_global_load_lds(
      (const __attribute__((address_space(1))) void*)g,
      (__attribute__((address_space(3))) void*)l, 16, 0, 0);
}

// ---------------- converters ----------------

__global__ void cvt_f32_bf16(const float* __restrict__ in, short* __restrict__ out) {
  int i = (blockIdx.x * 256 + threadIdx.x) * 4;
  float4 v = *(const float4*)(in + i);
  short4v o;
  o[0] = f2bf(v.x); o[1] = f2bf(v.y); o[2] = f2bf(v.z); o[3] = f2bf(v.w);
  *(short4v*)(out + i) = o;
}

// in [K][N] f32 -> out [N][K] bf16
__global__ void transpose_cvt(const float* __restrict__ in, short* __restrict__ out,
                              int K, int N) {
  __shared__ float tile[32][33];
  int bx = blockIdx.x * 32;  // n
  int by = blockIdx.y * 32;  // k
  int tx = threadIdx.x, ty = threadIdx.y;  // 32 x 8
#pragma unroll
  for (int i = 0; i < 32; i += 8)
    tile[ty + i][tx] = in[(size_t)(by + ty + i) * N + bx + tx];
  __syncthreads();
#pragma unroll
  for (int i = 0; i < 32; i += 8)
    out[(size_t)(bx + ty + i) * K + by + tx] = f2bf(tile[tx][ty + i]);
}

// ---------------- GEMM core (128x128 tile, BK=32, 4 waves) ----------------
// A [M][1024] bf16 row-major, Bt [N][1024] bf16 (B transposed).

#define GEMM_BODY(A_, Bt_)                                                        \
  __shared__ __align__(16) short As[128 * 32];                                    \
  __shared__ __align__(16) short Bs[128 * 32];                                    \
  const int tid = threadIdx.x;                                                    \
  const int wv = tid >> 6;                                                        \
  const int wr = wv >> 1, wc = wv & 1;                                            \
  const int ln = tid & 15, quad = (tid & 63) >> 4;                                \
  const int m0 = blockIdx.y * 128, n0 = blockIdx.x * 128;                         \
  f32x4 acc[4][4];                                                                \
  _Pragma("unroll") for (int i = 0; i < 4; ++i)                                   \
      _Pragma("unroll") for (int j = 0; j < 4; ++j)                               \
          acc[i][j] = (f32x4){0.f, 0.f, 0.f, 0.f};                                \
  for (int k0 = 0; k0 < 1024; k0 += 32) {                                         \
    _Pragma("unroll") for (int i = 0; i < 2; ++i) {                               \
      int cc = tid + i * 256;                                                     \
      int row = cc >> 2, part = cc & 3;                                           \
      gl_lds16(A_ + (size_t)(m0 + row) * 1024 + k0 + part * 8,                    \
               (char*)As + (wv * 64 + i * 256) * 16);                             \
      gl_lds16(Bt_ + (size_t)(n0 + row) * 1024 + k0 + part * 8,                   \
               (char*)Bs + (wv * 64 + i * 256) * 16);                             \
    }                                                                             \
    __syncthreads();                                                              \
    short8 af[4], bf[4];                                                          \
    _Pragma("unroll") for (int i = 0; i < 4; ++i)                                 \
        af[i] = *(const short8*)&As[(wr * 64 + i * 16 + ln) * 32 + quad * 8];     \
    _Pragma("unroll") for (int j = 0; j < 4; ++j)                                 \
        bf[j] = *(const short8*)&Bs[(wc * 64 + j * 16 + ln) * 32 + quad * 8];     \
    _Pragma("unroll") for (int i = 0; i < 4; ++i)                                 \
        _Pragma("unroll") for (int j = 0; j < 4; ++j)                             \
            acc[i][j] =                                                           \
                __builtin_amdgcn_mfma_f32_16x16x32_bf16(af[i], bf[j], acc[i][j],  \
                                                        0, 0, 0);                 \
    __syncthreads();                                                              \
  }

// QKV GEMM: M=8192 N=3072. Epilogue scatters to Q[B,H,T,D], K[B,H,T,D], Vt[B,H,D,T].
__global__ __launch_bounds__(256, 2) void gemm_qkv(
    const short* __restrict__ A, const short* __restrict__ Bt,
    const float* __restrict__ bias, short* __restrict__ Qb,
    short* __restrict__ Kb, short* __restrict__ Vtb) {
  GEMM_BODY(A, Bt)
#pragma unroll
  for (int i = 0; i < 4; ++i) {
#pragma unroll
    for (int j = 0; j < 4; ++j) {
      int n = n0 + wc * 64 + j * 16 + ln;
      int n2 = n & 1023;
      int hh = n2 >> 6, d = n2 & 63;
      float bv = bias[n];
#pragma unroll
      for (int r = 0; r < 4; ++r) {
        int m = m0 + wr * 64 + i * 16 + quad * 4 + r;
        int bb = m >> 11, t = m & 2047;
        short val = f2bf(acc[i][j][r] + bv);
        int bh = (bb << 4) + hh;
        if (n < 1024)
          Qb[((size_t)bh * 2048 + t) * 64 + d] = val;
        else if (n < 2048)
          Kb[((size_t)bh * 2048 + t) * 64 + d] = val;
        else
          Vtb[((size_t)bh * 64 + d) * 2048 + t] = val;
      }
    }
  }
}

// Proj GEMM: M=8192 N=1024, f32 output + bias.
__global__ __launch_bounds__(256, 2) void gemm_proj(
    const short* __restrict__ A, const short* __restrict__ Bt,
    const float* __restrict__ bias, float* __restrict__ out) {
  GEMM_BODY(A, Bt)
#pragma unroll
  for (int i = 0; i < 4; ++i) {
#pragma unroll
    for (int j = 0; j < 4; ++j) {
      int n = n0 + wc * 64 + j * 16 + ln;
      float bv = bias[n];
#pragma unroll
      for (int r = 0; r < 4; ++r) {
        int m = m0 + wr * 64 + i * 16 + quad * 4 + r;
        out[(size_t)m * 1024 + n] = acc[i][j][r] + bv;
      }
    }
  }
}

// ---------------- flash attention ----------------
// grid (T/64, B*H), block 256. Wave wv handles q rows [q0+wv*16, +16).
__global__ __launch_bounds__(256, 2) void flash_attn(
    const short* __restrict__ Qg_, const short* __restrict__ Kg_,
    const short* __restrict__ Vg_, short* __restrict__ Ob) {
  __shared__ __align__(16) short Ql[64 * 64];
  __shared__ __align__(16) short Kl[64 * 64];
  __shared__ __align__(16) short Vl[64 * 64];  // [d][t_local]
  __shared__ __align__(16) short Pl[4 * 16 * 64];
  const int tid = threadIdx.x;
  const int wv = tid >> 6, ln = tid & 15, quad = (tid & 63) >> 4;
  const int q0 = blockIdx.x * 64;
  const int bh = blockIdx.y;
  const short* Qg = Qg_ + (size_t)bh * 2048 * 64;
  const short* Kg = Kg_ + (size_t)bh * 2048 * 64;
  const short* Vg = Vg_ + (size_t)bh * 64 * 2048;

#pragma unroll
  for (int i = 0; i < 2; ++i) {
    int cc = tid + i * 256;
    int row = cc >> 3, part = cc & 7;
    gl_lds16(Qg + (size_t)(q0 + row) * 64 + part * 8,
             (char*)Ql + (wv * 64 + i * 256) * 16);
  }

  f32x4 Oa[4];
#pragma unroll
  for (int cb = 0; cb < 4; ++cb) Oa[cb] = (f32x4){0.f, 0.f, 0.f, 0.f};
  float mrow[4] = {-1e30f, -1e30f, -1e30f, -1e30f};
  float lrow[4] = {0.f, 0.f, 0.f, 0.f};

  const int ktmax = q0 >> 6;
  for (int kt = 0; kt <= ktmax; ++kt) {
#pragma unroll
    for (int i = 0; i < 2; ++i) {
      int cc = tid + i * 256;
      int row = cc >> 3, part = cc & 7;
      gl_lds16(Kg + (size_t)(kt * 64 + row) * 64 + part * 8,
               (char*)Kl + (wv * 64 + i * 256) * 16);
      gl_lds16(Vg + (size_t)row * 2048 + kt * 64 + part * 8,
               (char*)Vl + (wv * 64 + i * 256) * 16);
    }
    __syncthreads();

    // S = Q K^T for this wave's 16 q rows x 64 keys
    short8 qa0 = *(const short8*)&Ql[(wv * 16 + ln) * 64 + quad * 8];
    short8 qa1 = *(const short8*)&Ql[(wv * 16 + ln) * 64 + 32 + quad * 8];
    f32x4 S[4];
#pragma unroll
    for (int cb = 0; cb < 4; ++cb) {
      short8 kb0 = *(const short8*)&Kl[(cb * 16 + ln) * 64 + quad * 8];
      short8 kb1 = *(const short8*)&Kl[(cb * 16 + ln) * 64 + 32 + quad * 8];
      f32x4 s = (f32x4){0.f, 0.f, 0.f, 0.f};
      s = __builtin_amdgcn_mfma_f32_16x16x32_bf16(qa0, kb0, s, 0, 0, 0);
      s = __builtin_amdgcn_mfma_f32_16x16x32_bf16(qa1, kb1, s, 0, 0, 0);
      S[cb] = s;
    }

    // scale + causal mask + online softmax
    const int qb = q0 + wv * 16 + quad * 4;
    float mt[4] = {-1e30f, -1e30f, -1e30f, -1e30f};
#pragma unroll
    for (int cb = 0; cb < 4; ++cb) {
      int kg = kt * 64 + cb * 16 + ln;
#pragma unroll
      for (int r = 0; r < 4; ++r) {
        float s = S[cb][r] * 0.125f;
        s = (kg <= qb + r) ? s : -1e30f;
        S[cb][r] = s;
        mt[r] = fmaxf(mt[r], s);
      }
    }
#pragma unroll
    for (int r = 0; r < 4; ++r) {
#pragma unroll
      for (int off = 1; off < 16; off <<= 1)
        mt[r] = fmaxf(mt[r], __shfl_xor(mt[r], off));
      float mn = fmaxf(mrow[r], mt[r]);
      float al = __expf(mrow[r] - mn);
      mrow[r] = mn;
      float ps = 0.f;
#pragma unroll
      for (int cb = 0; cb < 4; ++cb) {
        float p = __expf(S[cb][r] - mn);
        S[cb][r] = p;
        ps += p;
      }
#pragma unroll
      for (int off = 1; off < 16; off <<= 1) ps += __shfl_xor(ps, off);
      lrow[r] = lrow[r] * al + ps;
#pragma unroll
      for (int cb = 0; cb < 4; ++cb) Oa[cb][r] *= al;
    }

    // P (C-layout) -> LDS bf16 -> A-layout fragments; wave-private region
    short* Pw = Pl + wv * 16 * 64;
#pragma unroll
    for (int cb = 0; cb < 4; ++cb)
#pragma unroll
      for (int r = 0; r < 4; ++r)
        Pw[(quad * 4 + r) * 64 + cb * 16 + ln] = f2bf(S[cb][r]);
    short8 pa0 = *(const short8*)&Pw[ln * 64 + quad * 8];
    short8 pa1 = *(const short8*)&Pw[ln * 64 + 32 + quad * 8];
#pragma unroll
    for (int cb = 0; cb < 4; ++cb) {
      short8 vb0 = *(const short8*)&Vl[(cb * 16 + ln) * 64 + quad * 8];
      short8 vb1 = *(const short8*)&Vl[(cb * 16 + ln) * 64 + 32 + quad * 8];
      Oa[cb] = __builtin_amdgcn_mfma_f32_16x16x32_bf16(pa0, vb0, Oa[cb], 0, 0, 0);
      Oa[cb] = __builtin_amdgcn_mfma_f32_16x16x32_bf16(pa1, vb1, Oa[cb], 0, 0, 0);
    }
    __syncthreads();
  }

  // epilogue: O / l -> Ob [B*T][C] bf16, c = h*64 + d
  const int bb = bh >> 4, h = bh & 15;
#pragma unroll
  for (int cb = 0; cb < 4; ++cb)
#pragma unroll
    for (int r = 0; r < 4; ++r) {
      int t = q0 + wv * 16 + quad * 4 + r;
      float v = Oa[cb][r] / lrow[r];
      Ob[((size_t)(bb * 2048 + t)) * 1024 + h * 64 + cb * 16 + ln] = f2bf(v);
    }
}

// ---------------- launcher ----------------

extern "C" void kernel_launch(void* const* d_in, const int* in_sizes, int n_in,
                              void* d_out, int out_size, void* d_ws, size_t ws_size,
                              hipStream_t stream) {
  const float* x      = (const float*)d_in[0];
  const float* w_attn = (const float*)d_in[1];
  const float* b_attn = (const float*)d_in[2];
  const float* w_proj = (const float*)d_in[3];
  const float* b_proj = (const float*)d_in[4];
  float* out = (float*)d_out;
  char* ws = (char*)d_ws;

  short* xb  = (short*)(ws);
  short* wat = (short*)(ws + 16777216);
  short* wpt = (short*)(ws + 23068672);
  short* Qb  = (short*)(ws + 25165824);
  short* Kb  = (short*)(ws + 41943040);
  short* Vtb = (short*)(ws + 58720256);
  short* Ob  = (short*)(ws + 75497472);

  cvt_f32_bf16<<<8192, 256, 0, stream>>>(x, xb);
  transpose_cvt<<<dim3(96, 32), dim3(32, 8), 0, stream>>>(w_attn, wat, 1024, 3072);
  transpose_cvt<<<dim3(32, 32), dim3(32, 8), 0, stream>>>(w_proj, wpt, 1024, 1024);
  gemm_qkv<<<dim3(24, 64), 256, 0, stream>>>(xb, wat, b_attn, Qb, Kb, Vtb);
  flash_attn<<<dim3(32, 64), 256, 0, stream>>>(Qb, Kb, Vtb, Ob);
  gemm_proj<<<dim3(8, 64), 256, 0, stream>>>(Ob, wpt, b_proj, out);
}

// Round 2
// 350.664 us; speedup vs baseline: 1.4511x; 1.4511x over previous
//
#include <hip/hip_runtime.h>
#include <hip/hip_bf16.h>

// CausalSelfAttention: B=4 T=2048 C=1024 H=16 D=64
// ws layout (bytes):
//   xb   @ 0         : x as bf16           [8192][1024]   16 MB
//   wat  @ 16777216  : w_attn^T bf16       [3072][1024]    6 MB
//   wpt  @ 23068672  : w_proj^T bf16       [1024][1024]    2 MB
//   Qb   @ 25165824  : Q bf16  [B,H,T,D]                  16 MB
//   Kb   @ 41943040  : K bf16  [B,H,T,D]                  16 MB
//   Vtb  @ 58720256  : V^T bf16 [B,H,D,T]                 16 MB
//   Ob   @ 75497472  : attn out bf16 [8192][1024]         16 MB

typedef float f32x4 __attribute__((ext_vector_type(4)));
typedef short short8 __attribute__((ext_vector_type(8)));
typedef short short4v __attribute__((ext_vector_type(4)));

__device__ __forceinline__ short f2bf(float f) {
  union { __hip_bfloat16 h; short s; } u;
  u.h = __float2bfloat16(f);
  return u.s;
}

__device__ __forceinline__ void gl_lds16(const void* g, void* l) {
  __builtin_amdgcn_global_load_lds(
      (const __attribute__((address_space(1))) void*)g,
      (__attribute__((address_space(3))) void*)l, 16, 0, 0);
}

// ---------------- converters ----------------

__global__ void cvt_f32_bf16(const float* __restrict__ in, short* __restrict__ out) {
  int i = (blockIdx.x * 256 + threadIdx.x) * 4;
  float4 v = *(const float4*)(in + i);
  short4v o;
  o[0] = f2bf(v.x); o[1] = f2bf(v.y); o[2] = f2bf(v.z); o[3] = f2bf(v.w);
  *(short4v*)(out + i) = o;
}

// in [K][N] f32 -> out [N][K] bf16
__global__ void transpose_cvt(const float* __restrict__ in, short* __restrict__ out,
                              int K, int N) {
  __shared__ float tile[32][33];
  int bx = blockIdx.x * 32;  // n
  int by = blockIdx.y * 32;  // k
  int tx = threadIdx.x, ty = threadIdx.y;  // 32 x 8
#pragma unroll
  for (int i = 0; i < 32; i += 8)
    tile[ty + i][tx] = in[(size_t)(by + ty + i) * N + bx + tx];
  __syncthreads();
#pragma unroll
  for (int i = 0; i < 32; i += 8)
    out[(size_t)(bx + ty + i) * K + by + tx] = f2bf(tile[tx][ty + i]);
}

// ---------------- GEMM core (128x128 tile, BK=32, 4 waves) ----------------
// A [M][1024] bf16 row-major, Bt [N][1024] bf16 (B transposed).

#define GEMM_BODY(A_, Bt_)                                                        \
  __shared__ __align__(16) short As[128 * 32];                                    \
  __shared__ __align__(16) short Bs[128 * 32];                                    \
  const int tid = threadIdx.x;                                                    \
  const int wv = tid >> 6;                                                        \
  const int wr = wv >> 1, wc = wv & 1;                                            \
  const int ln = tid & 15, quad = (tid & 63) >> 4;                                \
  const int m0 = blockIdx.y * 128, n0 = blockIdx.x * 128;                         \
  f32x4 acc[4][4];                                                                \
  _Pragma("unroll") for (int i = 0; i < 4; ++i)                                   \
      _Pragma("unroll") for (int j = 0; j < 4; ++j)                               \
          acc[i][j] = (f32x4){0.f, 0.f, 0.f, 0.f};                                \
  for (int k0 = 0; k0 < 1024; k0 += 32) {                                         \
    _Pragma("unroll") for (int i = 0; i < 2; ++i) {                               \
      int cc = tid + i * 256;                                                     \
      int row = cc >> 2, part = cc & 3;                                           \
      gl_lds16(A_ + (size_t)(m0 + row) * 1024 + k0 + part * 8,                    \
               (char*)As + (wv * 64 + i * 256) * 16);                             \
      gl_lds16(Bt_ + (size_t)(n0 + row) * 1024 + k0 + part * 8,                   \
               (char*)Bs + (wv * 64 + i * 256) * 16);                             \
    }                                                                             \
    __syncthreads();                                                              \
    short8 af[4], bf[4];                                                          \
    _Pragma("unroll") for (int i = 0; i < 4; ++i)                                 \
        af[i] = *(const short8*)&As[(wr * 64 + i * 16 + ln) * 32 + quad * 8];     \
    _Pragma("unroll") for (int j = 0; j < 4; ++j)                                 \
        bf[j] = *(const short8*)&Bs[(wc * 64 + j * 16 + ln) * 32 + quad * 8];     \
    _Pragma("unroll") for (int i = 0; i < 4; ++i)                                 \
        _Pragma("unroll") for (int j = 0; j < 4; ++j)                             \
            acc[i][j] =                                                           \
                __builtin_amdgcn_mfma_f32_16x16x32_bf16(af[i], bf[j], acc[i][j],  \
                                                        0, 0, 0);                 \
    __syncthreads();                                                              \
  }

// QKV GEMM: M=8192 N=3072. Epilogue scatters to Q[B,H,T,D], K[B,H,T,D], Vt[B,H,D,T].
__global__ __launch_bounds__(256, 2) void gemm_qkv(
    const short* __restrict__ A, const short* __restrict__ Bt,
    const float* __restrict__ bias, short* __restrict__ Qb,
    short* __restrict__ Kb, short* __restrict__ Vtb) {
  GEMM_BODY(A, Bt)
#pragma unroll
  for (int i = 0; i < 4; ++i) {
#pragma unroll
    for (int j = 0; j < 4; ++j) {
      int n = n0 + wc * 64 + j * 16 + ln;
      int n2 = n & 1023;
      int hh = n2 >> 6, d = n2 & 63;
      float bv = bias[n];
#pragma unroll
      for (int r = 0; r < 4; ++r) {
        int m = m0 + wr * 64 + i * 16 + quad * 4 + r;
        int bb = m >> 11, t = m & 2047;
        short val = f2bf(acc[i][j][r] + bv);
        int bh = (bb << 4) + hh;
        if (n < 1024)
          Qb[((size_t)bh * 2048 + t) * 64 + d] = val;
        else if (n < 2048)
          Kb[((size_t)bh * 2048 + t) * 64 + d] = val;
        else
          Vtb[((size_t)bh * 64 + d) * 2048 + t] = val;
      }
    }
  }
}

// Proj GEMM: M=8192 N=1024, f32 output + bias.
__global__ __launch_bounds__(256, 2) void gemm_proj(
    const short* __restrict__ A, const short* __restrict__ Bt,
    const float* __restrict__ bias, float* __restrict__ out) {
  GEMM_BODY(A, Bt)
#pragma unroll
  for (int i = 0; i < 4; ++i) {
#pragma unroll
    for (int j = 0; j < 4; ++j) {
      int n = n0 + wc * 64 + j * 16 + ln;
      float bv = bias[n];
#pragma unroll
      for (int r = 0; r < 4; ++r) {
        int m = m0 + wr * 64 + i * 16 + quad * 4 + r;
        out[(size_t)m * 1024 + n] = acc[i][j][r] + bv;
      }
    }
  }
}

// ---------------- flash attention (S^T formulation) ----------------
// grid (T/64, B*H), block 256. Wave wv handles q rows [q0+wv*16, +16).
// LDS rows padded to stride 72 shorts (144 B) -> bank windows rotate by 4/row,
// uniform 8 lanes/window on every b128 access (conflict-free).
// S^T = K.Q^T puts q on the lane index: softmax reduce = in-lane tree + 2 shfl.
// P^T C-layout rows land as 4x ds_write_b64 per lane; read back as A-frags (b128).
__global__ __launch_bounds__(256, 4) void flash_attn(
    const short* __restrict__ Qg_, const short* __restrict__ Kg_,
    const short* __restrict__ Vg_, short* __restrict__ Ob) {
  constexpr int STR = 72;
  __shared__ __align__(16) short Kl[64 * STR];   // [key][d]
  __shared__ __align__(16) short Vl[64 * STR];   // [d][key]  (V^T tile)
  __shared__ __align__(16) short Pl[64 * STR];   // wave wv rows [wv*16, +16): [q][key]
  const int tid = threadIdx.x;
  const int wv = tid >> 6, ln = tid & 15, quad = (tid & 63) >> 4;
  const int q0 = (gridDim.x - 1 - blockIdx.x) * 64;  // long blocks first (LPT)
  const int bh = blockIdx.y;
  const short* Qg = Qg_ + (size_t)bh * 2048 * 64;
  const short* Kg = Kg_ + (size_t)bh * 2048 * 64;
  const short* Vg = Vg_ + (size_t)bh * 64 * 2048;

  // Q B-fragments in registers for the whole kernel, pre-scaled by
  // 0.125*log2(e) so S is already in the exp2 domain.
  short8 qf[2];
#pragma unroll
  for (int ch = 0; ch < 2; ++ch) {
    short8 t = *(const short8*)(Qg + (size_t)(q0 + wv * 16 + ln) * 64 + ch * 32 + quad * 8);
#pragma unroll
    for (int j = 0; j < 8; ++j) {
      union { float f; unsigned u; } c;
      c.u = ((unsigned)(unsigned short)t[j]) << 16;
      c.f *= 0.1803368801f;  // 0.125 * log2(e)
      t[j] = (short)((c.u + 0x8000u) >> 16);
    }
    qf[ch] = t;
  }

  f32x4 Oa[4];
#pragma unroll
  for (int nb = 0; nb < 4; ++nb) Oa[nb] = (f32x4){0.f, 0.f, 0.f, 0.f};
  float mrow = -1e30f, lrow = 0.f;
  short* Pw = Pl + (size_t)(wv * 16 + ln) * STR;

  const int ktmax = q0 >> 6;
  for (int kt = 0; kt <= ktmax; ++kt) {
    // stage K tile [64 keys][64 d] and V^T tile [64 d][64 keys], padded stride
    const short* Kt = Kg + (size_t)kt * 64 * 64;
    short8 kreg[2], vreg[2];
#pragma unroll
    for (int i = 0; i < 2; ++i) {
      int cc = tid + i * 256, row = cc >> 3, part = cc & 7;
      kreg[i] = *(const short8*)(Kt + (size_t)row * 64 + part * 8);
      vreg[i] = *(const short8*)(Vg + (size_t)row * 2048 + kt * 64 + part * 8);
    }
    __syncthreads();  // previous iteration's LDS reads complete
#pragma unroll
    for (int i = 0; i < 2; ++i) {
      int cc = tid + i * 256, row = cc >> 3, part = cc & 7;
      *(short8*)&Kl[row * STR + part * 8] = kreg[i];
      *(short8*)&Vl[row * STR + part * 8] = vreg[i];
    }
    __syncthreads();

    // S^T = K.Q^T : St[kb][r] = s[q = ln][key = kb*16 + quad*4 + r]
    f32x4 St[4];
#pragma unroll
    for (int kb = 0; kb < 4; ++kb) {
      short8 ka0 = *(const short8*)&Kl[(kb * 16 + ln) * STR + quad * 8];
      short8 ka1 = *(const short8*)&Kl[(kb * 16 + ln) * STR + 32 + quad * 8];
      f32x4 s = (f32x4){0.f, 0.f, 0.f, 0.f};
      s = __builtin_amdgcn_mfma_f32_16x16x32_bf16(ka0, qf[0], s, 0, 0, 0);
      s = __builtin_amdgcn_mfma_f32_16x16x32_bf16(ka1, qf[1], s, 0, 0, 0);
      St[kb] = s;
    }

    if (kt == ktmax) {  // wave-uniform: only the diagonal tile masks
      const int qg = q0 + wv * 16 + ln;
#pragma unroll
      for (int kb = 0; kb < 4; ++kb)
#pragma unroll
        for (int r = 0; r < 4; ++r) {
          int key = kt * 64 + kb * 16 + quad * 4 + r;
          St[kb][r] = (key <= qg) ? St[kb][r] : -1e30f;
        }
    }

    // online softmax (exp2 domain); lane owns q=ln, 16 key-values
    float tmax = -1e30f;
#pragma unroll
    for (int kb = 0; kb < 4; ++kb)
#pragma unroll
      for (int r = 0; r < 4; ++r) tmax = fmaxf(tmax, St[kb][r]);
    tmax = fmaxf(tmax, __shfl_xor(tmax, 16));
    tmax = fmaxf(tmax, __shfl_xor(tmax, 32));
    float mnew = fmaxf(mrow, tmax);
    float alpha = __builtin_amdgcn_exp2f(mrow - mnew);
    float tsum = 0.f;
    short4v pf[4];
#pragma unroll
    for (int kb = 0; kb < 4; ++kb)
#pragma unroll
      for (int r = 0; r < 4; ++r) {
        float p = __builtin_amdgcn_exp2f(St[kb][r] - mnew);
        tsum += p;
        union { float f; unsigned u; } c;
        c.f = p;
        pf[kb][r] = (short)((c.u + 0x8000u) >> 16);
      }
    tsum += __shfl_xor(tsum, 16);
    tsum += __shfl_xor(tsum, 32);
    lrow = lrow * alpha + tsum;
    mrow = mnew;

    // P^T -> LDS (lane owns row q=ln): 4x b64 writes
#pragma unroll
    for (int kb = 0; kb < 4; ++kb)
      *(short4v*)&Pw[kb * 16 + quad * 4] = pf[kb];

    // rescale O by alpha broadcast to C-layout rows (q = quad*4 + r)
    float alq[4];
#pragma unroll
    for (int r = 0; r < 4; ++r) alq[r] = __shfl(alpha, quad * 4 + r);
#pragma unroll
    for (int nb = 0; nb < 4; ++nb)
#pragma unroll
      for (int r = 0; r < 4; ++r) Oa[nb][r] *= alq[r];

    // O += P.V : A-frag from Pl (own rows), B-frag from Vl (V^T rows = d)
    short8 pa0 = *(const short8*)&Pw[quad * 8];
    short8 pa1 = *(const short8*)&Pw[32 + quad * 8];
#pragma unroll
    for (int nb = 0; nb < 4; ++nb) {
      short8 vb0 = *(const short8*)&Vl[(nb * 16 + ln) * STR + quad * 8];
      short8 vb1 = *(const short8*)&Vl[(nb * 16 + ln) * STR + 32 + quad * 8];
      Oa[nb] = __builtin_amdgcn_mfma_f32_16x16x32_bf16(pa0, vb0, Oa[nb], 0, 0, 0);
      Oa[nb] = __builtin_amdgcn_mfma_f32_16x16x32_bf16(pa1, vb1, Oa[nb], 0, 0, 0);
    }
  }

  // epilogue: O / l -> Ob [B*T][C] bf16, c = h*64 + nb*16 + ln
  const int bb = bh >> 4, h = bh & 15;
  float lq[4];
#pragma unroll
  for (int r = 0; r < 4; ++r) lq[r] = __shfl(lrow, quad * 4 + r);
#pragma unroll
  for (int nb = 0; nb < 4; ++nb)
#pragma unroll
    for (int r = 0; r < 4; ++r) {
      int t = q0 + wv * 16 + quad * 4 + r;
      Ob[((size_t)(bb * 2048 + t)) * 1024 + h * 64 + nb * 16 + ln] =
          f2bf(Oa[nb][r] / lq[r]);
    }
}

// ---------------- launcher ----------------

extern "C" void kernel_launch(void* const* d_in, const int* in_sizes, int n_in,
                              void* d_out, int out_size, void* d_ws, size_t ws_size,
                              hipStream_t stream) {
  const float* x      = (const float*)d_in[0];
  const float* w_attn = (const float*)d_in[1];
  const float* b_attn = (const float*)d_in[2];
  const float* w_proj = (const float*)d_in[3];
  const float* b_proj = (const float*)d_in[4];
  float* out = (float*)d_out;
  char* ws = (char*)d_ws;

  short* xb  = (short*)(ws);
  short* wat = (short*)(ws + 16777216);
  short* wpt = (short*)(ws + 23068672);
  short* Qb  = (short*)(ws + 25165824);
  short* Kb  = (short*)(ws + 41943040);
  short* Vtb = (short*)(ws + 58720256);
  short* Ob  = (short*)(ws + 75497472);

  cvt_f32_bf16<<<8192, 256, 0, stream>>>(x, xb);
  transpose_cvt<<<dim3(96, 32), dim3(32, 8), 0, stream>>>(w_attn, wat, 1024, 3072);
  transpose_cvt<<<dim3(32, 32), dim3(32, 8), 0, stream>>>(w_proj, wpt, 1024, 1024);
  gemm_qkv<<<dim3(24, 64), 256, 0, stream>>>(xb, wat, b_attn, Qb, Kb, Vtb);
  flash_attn<<<dim3(32, 64), 256, 0, stream>>>(Qb, Kb, Vtb, Ob);
  gemm_proj<<<dim3(8, 64), 256, 0, stream>>>(Ob, wpt, b_proj, out);
}

// Round 4
// 315.418 us; speedup vs baseline: 1.6133x; 1.1117x over previous
//
#include <hip/hip_runtime.h>
#include <hip/hip_bf16.h>

// CausalSelfAttention: B=4 T=2048 C=1024 H=16 D=64
// ws layout (bytes):
//   xb   @ 0         : x as bf16           [8192][1024]   16 MB
//   wat  @ 16777216  : w_attn^T bf16       [3072][1024]    6 MB
//   wpt  @ 23068672  : w_proj^T bf16       [1024][1024]    2 MB
//   Qb   @ 25165824  : Q bf16 (pre-scaled by 0.125*log2e) [B,H,T,D] 16 MB
//   Kb   @ 41943040  : K bf16  [B,H,T,D]                  16 MB
//   Vtb  @ 58720256  : V^T bf16 [B,H,D,T]                 16 MB
//   Ob   @ 75497472  : attn out bf16 [8192][1024]         16 MB

typedef float f32x4 __attribute__((ext_vector_type(4)));
typedef short short8 __attribute__((ext_vector_type(8)));
typedef short short4v __attribute__((ext_vector_type(4)));

__device__ __forceinline__ short f2bf(float f) {
  union { __hip_bfloat16 h; short s; } u;
  u.h = __float2bfloat16(f);
  return u.s;
}

__device__ __forceinline__ void gl_lds16(const void* g, void* l) {
  __builtin_amdgcn_global_load_lds(
      (const __attribute__((address_space(1))) void*)g,
      (__attribute__((address_space(3))) void*)l, 16, 0, 0);
}

// ---------------- converters ----------------

__global__ void cvt_f32_bf16(const float* __restrict__ in, short* __restrict__ out) {
  int i = (blockIdx.x * 256 + threadIdx.x) * 4;
  float4 v = *(const float4*)(in + i);
  short4v o;
  o[0] = f2bf(v.x); o[1] = f2bf(v.y); o[2] = f2bf(v.z); o[3] = f2bf(v.w);
  *(short4v*)(out + i) = o;
}

// in [K][N] f32 -> out [N][K] bf16
__global__ void transpose_cvt(const float* __restrict__ in, short* __restrict__ out,
                              int K, int N) {
  __shared__ float tile[32][33];
  int bx = blockIdx.x * 32;  // n
  int by = blockIdx.y * 32;  // k
  int tx = threadIdx.x, ty = threadIdx.y;  // 32 x 8
#pragma unroll
  for (int i = 0; i < 32; i += 8)
    tile[ty + i][tx] = in[(size_t)(by + ty + i) * N + bx + tx];
  __syncthreads();
#pragma unroll
  for (int i = 0; i < 32; i += 8)
    out[(size_t)(bx + ty + i) * K + by + tx] = f2bf(tile[tx][ty + i]);
}

// ---------------- GEMM core (128x128 tile, BK=32, 4 waves) ----------------

#define GEMM_BODY(A_, Bt_)                                                        \
  __shared__ __align__(16) short As[128 * 32];                                    \
  __shared__ __align__(16) short Bs[128 * 32];                                    \
  const int tid = threadIdx.x;                                                    \
  const int wv = tid >> 6;                                                        \
  const int wr = wv >> 1, wc = wv & 1;                                            \
  const int ln = tid & 15, quad = (tid & 63) >> 4;                                \
  const int m0 = blockIdx.y * 128, n0 = blockIdx.x * 128;                         \
  f32x4 acc[4][4];                                                                \
  _Pragma("unroll") for (int i = 0; i < 4; ++i)                                   \
      _Pragma("unroll") for (int j = 0; j < 4; ++j)                               \
          acc[i][j] = (f32x4){0.f, 0.f, 0.f, 0.f};                                \
  for (int k0 = 0; k0 < 1024; k0 += 32) {                                         \
    _Pragma("unroll") for (int i = 0; i < 2; ++i) {                               \
      int cc = tid + i * 256;                                                     \
      int row = cc >> 2, part = cc & 3;                                           \
      gl_lds16(A_ + (size_t)(m0 + row) * 1024 + k0 + part * 8,                    \
               (char*)As + (wv * 64 + i * 256) * 16);                             \
      gl_lds16(Bt_ + (size_t)(n0 + row) * 1024 + k0 + part * 8,                   \
               (char*)Bs + (wv * 64 + i * 256) * 16);                             \
    }                                                                             \
    __syncthreads();                                                              \
    short8 af[4], bf[4];                                                          \
    _Pragma("unroll") for (int i = 0; i < 4; ++i)                                 \
        af[i] = *(const short8*)&As[(wr * 64 + i * 16 + ln) * 32 + quad * 8];     \
    _Pragma("unroll") for (int j = 0; j < 4; ++j)                                 \
        bf[j] = *(const short8*)&Bs[(wc * 64 + j * 16 + ln) * 32 + quad * 8];     \
    _Pragma("unroll") for (int i = 0; i < 4; ++i)                                 \
        _Pragma("unroll") for (int j = 0; j < 4; ++j)                             \
            acc[i][j] =                                                           \
                __builtin_amdgcn_mfma_f32_16x16x32_bf16(af[i], bf[j], acc[i][j],  \
                                                        0, 0, 0);                 \
    __syncthreads();                                                              \
  }

// QKV GEMM. Q is pre-scaled by 0.125*log2(e) here (free in epilogue).
__global__ __launch_bounds__(256, 2) void gemm_qkv(
    const short* __restrict__ A, const short* __restrict__ Bt,
    const float* __restrict__ bias, short* __restrict__ Qb,
    short* __restrict__ Kb, short* __restrict__ Vtb) {
  GEMM_BODY(A, Bt)
#pragma unroll
  for (int i = 0; i < 4; ++i) {
#pragma unroll
    for (int j = 0; j < 4; ++j) {
      int n = n0 + wc * 64 + j * 16 + ln;
      int n2 = n & 1023;
      int hh = n2 >> 6, d = n2 & 63;
      float bv = bias[n];
#pragma unroll
      for (int r = 0; r < 4; ++r) {
        int m = m0 + wr * 64 + i * 16 + quad * 4 + r;
        int bb = m >> 11, t = m & 2047;
        float o = acc[i][j][r] + bv;
        int bh = (bb << 4) + hh;
        if (n < 1024)
          Qb[((size_t)bh * 2048 + t) * 64 + d] = f2bf(o * 0.18033688f);
        else if (n < 2048)
          Kb[((size_t)bh * 2048 + t) * 64 + d] = f2bf(o);
        else
          Vtb[((size_t)bh * 64 + d) * 2048 + t] = f2bf(o);
      }
    }
  }
}

__global__ __launch_bounds__(256, 2) void gemm_proj(
    const short* __restrict__ A, const short* __restrict__ Bt,
    const float* __restrict__ bias, float* __restrict__ out) {
  GEMM_BODY(A, Bt)
#pragma unroll
  for (int i = 0; i < 4; ++i) {
#pragma unroll
    for (int j = 0; j < 4; ++j) {
      int n = n0 + wc * 64 + j * 16 + ln;
      float bv = bias[n];
#pragma unroll
      for (int r = 0; r < 4; ++r) {
        int m = m0 + wr * 64 + i * 16 + quad * 4 + r;
        out[(size_t)m * 1024 + n] = acc[i][j][r] + bv;
      }
    }
  }
}

// ---------------- flash attention (no-max exp2 softmax, register P) --------
// grid (T/128, B*H), block 256. Wave wv owns 32 q rows (2 halves of 16).
// S^T = K.Q^T via 16x16x32 (q on lanes). P^T exits in exactly the B-frag
// layout of mfma_f32_16x16x16bf16_1k (n=ln=q, k=quad*4+r=key), so
// O^T = V^T.P^T consumes P from registers: no P LDS round-trip, no shuffles.
// No online max: scores are pre-scaled into exp2 domain, |s| << 127, and the
// common 2^m factor cancels in O/l. l accumulates per-lane, reduced at end.
// K/V register-prefetch for kt+1 overlaps the whole compute phase.
__global__ __launch_bounds__(256, 3) void flash_attn(
    const short* __restrict__ Qg_, const short* __restrict__ Kg_,
    const short* __restrict__ Vg_, short* __restrict__ Ob) {
  constexpr int STR = 72;  // padded: bank window rotates 4/row, conflict-free
  __shared__ __align__(16) short Kl[64 * STR];   // [key][d]
  __shared__ __align__(16) short Vl[64 * STR];   // [d][key]
  const int tid = threadIdx.x;
  const int wv = tid >> 6, ln = tid & 15, quad = (tid & 63) >> 4;
  const int q0 = (gridDim.x - 1 - blockIdx.x) * 128;  // long blocks first
  const int bh = blockIdx.y;
  const short* Qg = Qg_ + (size_t)bh * 2048 * 64;
  const short* Kg = Kg_ + (size_t)bh * 2048 * 64;
  const short* Vg = Vg_ + (size_t)bh * 64 * 2048;
  const int qbase = q0 + wv * 32;

  // Q B-frags (pre-scaled in gemm_qkv): held in registers for whole kernel
  short8 qf[2][2];
#pragma unroll
  for (int h = 0; h < 2; ++h)
#pragma unroll
    for (int ch = 0; ch < 2; ++ch)
      qf[h][ch] = *(const short8*)(Qg + (size_t)(qbase + h * 16 + ln) * 64 +
                                   ch * 32 + quad * 8);

  f32x4 Oacc[2][4];
#pragma unroll
  for (int h = 0; h < 2; ++h)
#pragma unroll
    for (int mt = 0; mt < 4; ++mt) Oacc[h][mt] = (f32x4){0.f, 0.f, 0.f, 0.f};
  float lpart[2] = {0.f, 0.f};

  const int ktmax = (q0 + 127) >> 6;
  short8 kreg[2], vreg[2];
  const int srow = tid >> 3, spart = tid & 7;

#define LOADKV(KT)                                                              \
  {                                                                             \
    const short* Kt = Kg + (size_t)(KT) * 64 * 64;                              \
    _Pragma("unroll") for (int i = 0; i < 2; ++i) {                             \
      kreg[i] = *(const short8*)(Kt + (size_t)(srow + i * 32) * 64 + spart * 8);\
      vreg[i] = *(const short8*)(Vg + (size_t)(srow + i * 32) * 2048 +          \
                                 (KT) * 64 + spart * 8);                        \
    }                                                                           \
  }

  LOADKV(0)
  for (int kt = 0; kt <= ktmax; ++kt) {
    __syncthreads();  // previous iteration's LDS readers done
#pragma unroll
    for (int i = 0; i < 2; ++i) {
      *(short8*)&Kl[(srow + i * 32) * STR + spart * 8] = kreg[i];
      *(short8*)&Vl[(srow + i * 32) * STR + spart * 8] = vreg[i];
    }
    __syncthreads();
    if (kt < ktmax) LOADKV(kt + 1)  // overlaps all compute below

    if (kt * 64 <= qbase + 31) {  // wave-uniform: skip fully-masked tiles
      // S^T = K.Q^T
      f32x4 St[2][4];
#pragma unroll
      for (int h = 0; h < 2; ++h)
#pragma unroll
        for (int kb = 0; kb < 4; ++kb) St[h][kb] = (f32x4){0.f, 0.f, 0.f, 0.f};
#pragma unroll
      for (int kb = 0; kb < 4; ++kb) {
        short8 ka0 = *(const short8*)&Kl[(kb * 16 + ln) * STR + quad * 8];
        short8 ka1 = *(const short8*)&Kl[(kb * 16 + ln) * STR + 32 + quad * 8];
#pragma unroll
        for (int h = 0; h < 2; ++h) {
          St[h][kb] = __builtin_amdgcn_mfma_f32_16x16x32_bf16(ka0, qf[h][0],
                                                              St[h][kb], 0, 0, 0);
          St[h][kb] = __builtin_amdgcn_mfma_f32_16x16x32_bf16(ka1, qf[h][1],
                                                              St[h][kb], 0, 0, 0);
        }
      }

      // p = exp2(s); accumulate l; pack P to bf16 (already B-frag layout)
      short4v pf[2][4];
#pragma unroll
      for (int h = 0; h < 2; ++h) {
        const bool needmask = kt * 64 + 63 > qbase + h * 16;
        const int qg = qbase + h * 16 + ln;
#pragma unroll
        for (int kb = 0; kb < 4; ++kb)
#pragma unroll
          for (int r = 0; r < 4; ++r) {
            float s = St[h][kb][r];
            if (needmask) {
              int key = kt * 64 + kb * 16 + quad * 4 + r;
              s = (key <= qg) ? s : -1e30f;
            }
            float p = __builtin_amdgcn_exp2f(s);
            lpart[h] += p;
            union { float f; unsigned u; } c;
            c.f = p;
            pf[h][kb][r] = (short)((c.u + 0x8000u) >> 16);
          }
      }

      // O^T += V^T . P^T  (K=16 MFMA, P straight from registers)
#pragma unroll
      for (int kb = 0; kb < 4; ++kb)
#pragma unroll
        for (int mt = 0; mt < 4; ++mt) {
          short4v va =
              *(const short4v*)&Vl[(mt * 16 + ln) * STR + kb * 16 + quad * 4];
#pragma unroll
          for (int h = 0; h < 2; ++h)
            Oacc[h][mt] = __builtin_amdgcn_mfma_f32_16x16x16bf16_1k(
                va, pf[h][kb], Oacc[h][mt], 0, 0, 0);
        }
    }
  }

  // epilogue: reduce l across quads (only shuffles in the kernel), write O/l.
  // O^T C-layout: col=ln=q, row=quad*4+r=d  -> b64 stores
  const int bb = bh >> 4, hh = bh & 15;
#pragma unroll
  for (int h = 0; h < 2; ++h) {
    float l = lpart[h];
    l += __shfl_xor(l, 16);
    l += __shfl_xor(l, 32);
    float rl = 1.0f / l;
    int t = qbase + h * 16 + ln;
#pragma unroll
    for (int mt = 0; mt < 4; ++mt) {
      short4v o;
#pragma unroll
      for (int r = 0; r < 4; ++r) o[r] = f2bf(Oacc[h][mt][r] * rl);
      *(short4v*)(Ob + ((size_t)(bb * 2048 + t)) * 1024 + hh * 64 + mt * 16 +
                  quad * 4) = o;
    }
  }
}

// ---------------- launcher ----------------

extern "C" void kernel_launch(void* const* d_in, const int* in_sizes, int n_in,
                              void* d_out, int out_size, void* d_ws, size_t ws_size,
                              hipStream_t stream) {
  const float* x      = (const float*)d_in[0];
  const float* w_attn = (const float*)d_in[1];
  const float* b_attn = (const float*)d_in[2];
  const float* w_proj = (const float*)d_in[3];
  const float* b_proj = (const float*)d_in[4];
  float* out = (float*)d_out;
  char* ws = (char*)d_ws;

  short* xb  = (short*)(ws);
  short* wat = (short*)(ws + 16777216);
  short* wpt = (short*)(ws + 23068672);
  short* Qb  = (short*)(ws + 25165824);
  short* Kb  = (short*)(ws + 41943040);
  short* Vtb = (short*)(ws + 58720256);
  short* Ob  = (short*)(ws + 75497472);

  cvt_f32_bf16<<<8192, 256, 0, stream>>>(x, xb);
  transpose_cvt<<<dim3(96, 32), dim3(32, 8), 0, stream>>>(w_attn, wat, 1024, 3072);
  transpose_cvt<<<dim3(32, 32), dim3(32, 8), 0, stream>>>(w_proj, wpt, 1024, 1024);
  gemm_qkv<<<dim3(24, 64), 256, 0, stream>>>(xb, wat, b_attn, Qb, Kb, Vtb);
  flash_attn<<<dim3(16, 64), 256, 0, stream>>>(Qb, Kb, Vtb, Ob);
  gemm_proj<<<dim3(8, 64), 256, 0, stream>>>(Ob, wpt, b_proj, out);
}

// Round 5
// 269.886 us; speedup vs baseline: 1.8855x; 1.1687x over previous
//
#include <hip/hip_runtime.h>
#include <hip/hip_bf16.h>

// CausalSelfAttention: B=4 T=2048 C=1024 H=16 D=64
// ws layout (bytes):
//   xb   @ 0         : x as bf16           [8192][1024]   16 MB
//   wat  @ 16777216  : w_attn^T bf16       [3072][1024]    6 MB
//   wpt  @ 23068672  : w_proj^T bf16       [1024][1024]    2 MB
//   Qb   @ 25165824  : Q bf16 (pre-scaled by 0.125*log2e) [B,H,T,D] 16 MB
//   Kb   @ 41943040  : K bf16  [B,H,T,D]                  16 MB
//   Vtb  @ 58720256  : V^T bf16 [B,H,D,T]                 16 MB
//   Ob   @ 75497472  : dual-use: V [B,H,T,D] staging (pre-flash),
//                      then attn out bf16 [8192][1024]    16 MB

typedef float f32x4 __attribute__((ext_vector_type(4)));
typedef short short8 __attribute__((ext_vector_type(8)));
typedef short short4v __attribute__((ext_vector_type(4)));

__device__ __forceinline__ short f2bf(float f) {
  union { __hip_bfloat16 h; short s; } u;
  u.h = __float2bfloat16(f);
  return u.s;
}

__device__ __forceinline__ void gl_lds16(const void* g, void* l) {
  __builtin_amdgcn_global_load_lds(
      (const __attribute__((address_space(1))) void*)g,
      (__attribute__((address_space(3))) void*)l, 16, 0, 0);
}

// ---------------- converters ----------------

__global__ void cvt_f32_bf16(const float* __restrict__ in, short* __restrict__ out) {
  int i = (blockIdx.x * 256 + threadIdx.x) * 4;
  float4 v = *(const float4*)(in + i);
  short4v o;
  o[0] = f2bf(v.x); o[1] = f2bf(v.y); o[2] = f2bf(v.z); o[3] = f2bf(v.w);
  *(short4v*)(out + i) = o;
}

// in [K][N] f32 -> out [N][K] bf16
__global__ void transpose_cvt(const float* __restrict__ in, short* __restrict__ out,
                              int K, int N) {
  __shared__ float tile[32][33];
  int bx = blockIdx.x * 32;  // n
  int by = blockIdx.y * 32;  // k
  int tx = threadIdx.x, ty = threadIdx.y;  // 32 x 8
#pragma unroll
  for (int i = 0; i < 32; i += 8)
    tile[ty + i][tx] = in[(size_t)(by + ty + i) * N + bx + tx];
  __syncthreads();
#pragma unroll
  for (int i = 0; i < 32; i += 8)
    out[(size_t)(bx + ty + i) * K + by + tx] = f2bf(tile[tx][ty + i]);
}

// V [bh][2048 t][64 d] bf16 -> V^T [bh][64 d][2048 t] bf16 (coalesced both ways)
__global__ void transpose_v(const short* __restrict__ in, short* __restrict__ out) {
  __shared__ short tile[32][33];
  const int bh = blockIdx.z;
  const int d0 = blockIdx.x * 32, t0 = blockIdx.y * 32;
  const short* src = in + (size_t)bh * 2048 * 64;
  short* dst = out + (size_t)bh * 64 * 2048;
  int tx = threadIdx.x, ty = threadIdx.y;  // 32 x 8
#pragma unroll
  for (int i = 0; i < 4; ++i)
    tile[ty + i * 8][tx] = src[(size_t)(t0 + ty + i * 8) * 64 + d0 + tx];
  __syncthreads();
#pragma unroll
  for (int i = 0; i < 4; ++i)
    dst[(size_t)(d0 + ty + i * 8) * 2048 + t0 + tx] = tile[tx][ty + i * 8];
}

// ---------------- GEMM core (128x128 tile, BK=32, 4 waves) ----------------

#define GEMM_BODY(A_, Bt_)                                                        \
  __shared__ __align__(16) short As[128 * 32];                                    \
  __shared__ __align__(16) short Bs[128 * 32];                                    \
  const int tid = threadIdx.x;                                                    \
  const int wv = tid >> 6;                                                        \
  const int wr = wv >> 1, wc = wv & 1;                                            \
  const int ln = tid & 15, quad = (tid & 63) >> 4;                                \
  const int m0 = blockIdx.y * 128, n0 = blockIdx.x * 128;                         \
  f32x4 acc[4][4];                                                                \
  _Pragma("unroll") for (int i = 0; i < 4; ++i)                                   \
      _Pragma("unroll") for (int j = 0; j < 4; ++j)                               \
          acc[i][j] = (f32x4){0.f, 0.f, 0.f, 0.f};                                \
  for (int k0 = 0; k0 < 1024; k0 += 32) {                                         \
    _Pragma("unroll") for (int i = 0; i < 2; ++i) {                               \
      int cc = tid + i * 256;                                                     \
      int row = cc >> 2, part = cc & 3;                                           \
      gl_lds16(A_ + (size_t)(m0 + row) * 1024 + k0 + part * 8,                    \
               (char*)As + (wv * 64 + i * 256) * 16);                             \
      gl_lds16(Bt_ + (size_t)(n0 + row) * 1024 + k0 + part * 8,                   \
               (char*)Bs + (wv * 64 + i * 256) * 16);                             \
    }                                                                             \
    __syncthreads();                                                              \
    short8 af[4], bf[4];                                                          \
    _Pragma("unroll") for (int i = 0; i < 4; ++i)                                 \
        af[i] = *(const short8*)&As[(wr * 64 + i * 16 + ln) * 32 + quad * 8];     \
    _Pragma("unroll") for (int j = 0; j < 4; ++j)                                 \
        bf[j] = *(const short8*)&Bs[(wc * 64 + j * 16 + ln) * 32 + quad * 8];     \
    _Pragma("unroll") for (int i = 0; i < 4; ++i)                                 \
        _Pragma("unroll") for (int j = 0; j < 4; ++j)                             \
            acc[i][j] =                                                           \
                __builtin_amdgcn_mfma_f32_16x16x32_bf16(af[i], bf[j], acc[i][j],  \
                                                        0, 0, 0);                 \
    __syncthreads();                                                              \
  }

// QKV GEMM. Q pre-scaled by 0.125*log2(e). V stored coalesced [B,H,T,D]
// (transpose_v produces V^T afterwards; the old in-epilogue V^T scatter was
// 2B stores at stride 4KB -> write amplification).
__global__ __launch_bounds__(256, 2) void gemm_qkv(
    const short* __restrict__ A, const short* __restrict__ Bt,
    const float* __restrict__ bias, short* __restrict__ Qb,
    short* __restrict__ Kb, short* __restrict__ Vb) {
  GEMM_BODY(A, Bt)
#pragma unroll
  for (int i = 0; i < 4; ++i) {
#pragma unroll
    for (int j = 0; j < 4; ++j) {
      int n = n0 + wc * 64 + j * 16 + ln;
      int n2 = n & 1023;
      int hh = n2 >> 6, d = n2 & 63;
      float bv = bias[n];
#pragma unroll
      for (int r = 0; r < 4; ++r) {
        int m = m0 + wr * 64 + i * 16 + quad * 4 + r;
        int bb = m >> 11, t = m & 2047;
        float o = acc[i][j][r] + bv;
        size_t idx = ((size_t)((bb << 4) + hh) * 2048 + t) * 64 + d;
        if (n < 1024)
          Qb[idx] = f2bf(o * 0.18033688f);
        else if (n < 2048)
          Kb[idx] = f2bf(o);
        else
          Vb[idx] = f2bf(o);
      }
    }
  }
}

__global__ __launch_bounds__(256, 2) void gemm_proj(
    const short* __restrict__ A, const short* __restrict__ Bt,
    const float* __restrict__ bias, float* __restrict__ out) {
  GEMM_BODY(A, Bt)
#pragma unroll
  for (int i = 0; i < 4; ++i) {
#pragma unroll
    for (int j = 0; j < 4; ++j) {
      int n = n0 + wc * 64 + j * 16 + ln;
      float bv = bias[n];
#pragma unroll
      for (int r = 0; r < 4; ++r) {
        int m = m0 + wr * 64 + i * 16 + quad * 4 + r;
        out[(size_t)m * 1024 + n] = acc[i][j][r] + bv;
      }
    }
  }
}

// ---------------- flash attention -----------------------------------------
// Balanced persistent pairing: qtile i costs 2i+2 kt-iters; block p handles
// qtiles {15-pair, pair} (pair = p>>6) -> exactly 34 iters per block.
// Grid 512 = 2 blocks/CU, no drain tail. bh = p&63 keeps a head's 8 blocks
// on one XCD (K/V L2 reuse). LDS double-buffered: one barrier per iter,
// staging writes overlap compute; global prefetch issued one iter ahead.
// No-max exp2 softmax (scores pre-scaled; 2^m cancels in O/l), P^T stays in
// registers (S^T C-layout == 16x16x16 B-frag layout).
__global__ __launch_bounds__(256, 2) void flash_attn(
    const short* __restrict__ Qg_, const short* __restrict__ Kg_,
    const short* __restrict__ Vg_, short* __restrict__ Ob) {
  constexpr int STR = 72;  // padded rows: rotates bank window 4/row
  __shared__ __align__(16) short Kl[2][64 * STR];
  __shared__ __align__(16) short Vl[2][64 * STR];
  const int tid = threadIdx.x;
  const int wv = tid >> 6, ln = tid & 15, quad = (tid & 63) >> 4;
  const int bh = blockIdx.x & 63;
  const int pair = blockIdx.x >> 6;
  const short* Qg = Qg_ + (size_t)bh * 2048 * 64;
  const short* Kg = Kg_ + (size_t)bh * 2048 * 64;
  const short* Vg = Vg_ + (size_t)bh * 64 * 2048;
  const int srow = tid >> 3, spart = tid & 7;
  const int bb = bh >> 4, hh = bh & 15;

  short8 kreg[2], vreg[2];

#define LOADKV(KT)                                                              \
  {                                                                             \
    const short* Kt = Kg + (size_t)(KT) * 64 * 64;                              \
    _Pragma("unroll") for (int i = 0; i < 2; ++i) {                             \
      kreg[i] = *(const short8*)(Kt + (size_t)(srow + i * 32) * 64 + spart * 8);\
      vreg[i] = *(const short8*)(Vg + (size_t)(srow + i * 32) * 2048 +          \
                                 (KT) * 64 + spart * 8);                        \
    }                                                                           \
  }
#define WRITEKV(BUF)                                                            \
  _Pragma("unroll") for (int i = 0; i < 2; ++i) {                               \
    *(short8*)&Kl[BUF][(srow + i * 32) * STR + spart * 8] = kreg[i];            \
    *(short8*)&Vl[BUF][(srow + i * 32) * STR + spart * 8] = vreg[i];            \
  }

#pragma unroll
  for (int it = 0; it < 2; ++it) {
    const int qt = it ? pair : (15 - pair);  // long item first
    const int q0 = qt * 128;
    const int qbase = q0 + wv * 32;
    const int nkt = (q0 >> 6) + 2;

    // Q B-frags in registers (pre-scaled in gemm_qkv)
    short8 qf[2][2];
#pragma unroll
    for (int h = 0; h < 2; ++h)
#pragma unroll
      for (int ch = 0; ch < 2; ++ch)
        qf[h][ch] = *(const short8*)(Qg + (size_t)(qbase + h * 16 + ln) * 64 +
                                     ch * 32 + quad * 8);

    f32x4 Oacc[2][4];
#pragma unroll
    for (int h = 0; h < 2; ++h)
#pragma unroll
      for (int mt = 0; mt < 4; ++mt) Oacc[h][mt] = (f32x4){0.f, 0.f, 0.f, 0.f};
    float lpart[2] = {0.f, 0.f};

    LOADKV(0)
    __syncthreads();  // previous item's readers of buf0 done
    WRITEKV(0)
    LOADKV(1)

    for (int kt = 0; kt < nkt; ++kt) {
      __syncthreads();  // buf[kt&1] staged; prev readers of buf[(kt+1)&1] done
      const short* Kcur = Kl[kt & 1];
      const short* Vcur = Vl[kt & 1];
      if (kt + 1 < nkt) {
        WRITEKV((kt + 1) & 1)  // overlaps this iter's compute reads
        if (kt + 2 < nkt) LOADKV(kt + 2)
      }

      if (kt * 64 <= qbase + 31) {  // wave-uniform skip of fully-masked tiles
        // S^T = K.Q^T (q on lanes)
        f32x4 St[2][4];
#pragma unroll
        for (int h = 0; h < 2; ++h)
#pragma unroll
          for (int kb = 0; kb < 4; ++kb) St[h][kb] = (f32x4){0.f, 0.f, 0.f, 0.f};
#pragma unroll
        for (int kb = 0; kb < 4; ++kb) {
          short8 ka0 = *(const short8*)&Kcur[(kb * 16 + ln) * STR + quad * 8];
          short8 ka1 = *(const short8*)&Kcur[(kb * 16 + ln) * STR + 32 + quad * 8];
#pragma unroll
          for (int h = 0; h < 2; ++h) {
            St[h][kb] = __builtin_amdgcn_mfma_f32_16x16x32_bf16(
                ka0, qf[h][0], St[h][kb], 0, 0, 0);
            St[h][kb] = __builtin_amdgcn_mfma_f32_16x16x32_bf16(
                ka1, qf[h][1], St[h][kb], 0, 0, 0);
          }
        }

        // p = exp2(s); accumulate l; pack pairs via v_cvt_pk_bf16_f32
        short4v pf[2][4];
#pragma unroll
        for (int h = 0; h < 2; ++h) {
          const bool needmask = kt * 64 + 63 > qbase + h * 16;
          const int qg = qbase + h * 16 + ln;
#pragma unroll
          for (int kb = 0; kb < 4; ++kb) {
            float p[4];
#pragma unroll
            for (int r = 0; r < 4; ++r) {
              float s = St[h][kb][r];
              if (needmask) {
                int key = kt * 64 + kb * 16 + quad * 4 + r;
                s = (key <= qg) ? s : -1e30f;
              }
              p[r] = __builtin_amdgcn_exp2f(s);
              lpart[h] += p[r];
            }
            union { __hip_bfloat162 b2; unsigned u; } w0, w1;
            w0.b2 = __float22bfloat162_rn(make_float2(p[0], p[1]));
            w1.b2 = __float22bfloat162_rn(make_float2(p[2], p[3]));
            union { short4v s4; unsigned u2[2]; } m;
            m.u2[0] = w0.u; m.u2[1] = w1.u;
            pf[h][kb] = m.s4;
          }
        }

        // O^T += V^T . P^T (P from registers, K=16 MFMA)
#pragma unroll
        for (int kb = 0; kb < 4; ++kb)
#pragma unroll
          for (int mt = 0; mt < 4; ++mt) {
            short4v va =
                *(const short4v*)&Vcur[(mt * 16 + ln) * STR + kb * 16 + quad * 4];
#pragma unroll
            for (int h = 0; h < 2; ++h)
              Oacc[h][mt] = __builtin_amdgcn_mfma_f32_16x16x16bf16_1k(
                  va, pf[h][kb], Oacc[h][mt], 0, 0, 0);
          }
      }
    }

    // epilogue: reduce l across quads, write O/l (O^T C-layout -> b64 stores)
#pragma unroll
    for (int h = 0; h < 2; ++h) {
      float l = lpart[h];
      l += __shfl_xor(l, 16);
      l += __shfl_xor(l, 32);
      float rl = 1.0f / l;
      int t = qbase + h * 16 + ln;
#pragma unroll
      for (int mt = 0; mt < 4; ++mt) {
        short4v o;
#pragma unroll
        for (int r = 0; r < 4; ++r) o[r] = f2bf(Oacc[h][mt][r] * rl);
        *(short4v*)(Ob + ((size_t)(bb * 2048 + t)) * 1024 + hh * 64 + mt * 16 +
                    quad * 4) = o;
      }
    }
  }
#undef LOADKV
#undef WRITEKV
}

// ---------------- launcher ----------------

extern "C" void kernel_launch(void* const* d_in, const int* in_sizes, int n_in,
                              void* d_out, int out_size, void* d_ws, size_t ws_size,
                              hipStream_t stream) {
  const float* x      = (const float*)d_in[0];
  const float* w_attn = (const float*)d_in[1];
  const float* b_attn = (const float*)d_in[2];
  const float* w_proj = (const float*)d_in[3];
  const float* b_proj = (const float*)d_in[4];
  float* out = (float*)d_out;
  char* ws = (char*)d_ws;

  short* xb  = (short*)(ws);
  short* wat = (short*)(ws + 16777216);
  short* wpt = (short*)(ws + 23068672);
  short* Qb  = (short*)(ws + 25165824);
  short* Kb  = (short*)(ws + 41943040);
  short* Vtb = (short*)(ws + 58720256);
  short* Ob  = (short*)(ws + 75497472);
  short* Vb  = Ob;  // V [B,H,T,D] staging lives in Ob region until flash runs

  cvt_f32_bf16<<<8192, 256, 0, stream>>>(x, xb);
  transpose_cvt<<<dim3(96, 32), dim3(32, 8), 0, stream>>>(w_attn, wat, 1024, 3072);
  transpose_cvt<<<dim3(32, 32), dim3(32, 8), 0, stream>>>(w_proj, wpt, 1024, 1024);
  gemm_qkv<<<dim3(24, 64), 256, 0, stream>>>(xb, wat, b_attn, Qb, Kb, Vb);
  transpose_v<<<dim3(2, 64, 64), dim3(32, 8), 0, stream>>>(Vb, Vtb);
  flash_attn<<<512, 256, 0, stream>>>(Qb, Kb, Vtb, Ob);
  gemm_proj<<<dim3(8, 64), 256, 0, stream>>>(Ob, wpt, b_proj, out);
}